// Round 13
// baseline (1448.161 us; speedup 1.0000x reference)
//
#include <hip/hip_runtime.h>
#include <math.h>

#define N_ 32
#define T_ 417
#define V_ 25
#define D_ 2
#define NODES_ 10425          // T_*V_
#define E_ 80000
#define EN_ (E_ + NODES_)     // 90425 (edges + self loops)
#define HID_ 20
#define LH_ 50
#define NH_ 5
#define HD_ 10
#define FF_ 2048
#define NL_ 3
#define CO_ 85
#define NC_ 6
#define NS_ 2
#define SZ_ 83
#define EPS_ 1e-5f
#define NCH_ 11               // scan chunks of 1024 covering NODES_
#define LCH_ 32               // LSTM steps staged per LDS chunk
#define NBK_ 64               // moment accumulation buckets

__device__ inline float sane(float v){
  return (v == v && fabsf(v) < 1e30f) ? v : 0.f;
}

__device__ inline float wave_sum(float v){
  #pragma unroll
  for (int off = 32; off > 0; off >>= 1) v += __shfl_xor(v, off, 64);
  return v;
}

// ---------------- init: copy x -> x1, zero deg + loss accumulators + moment buckets
__global__ void k_init(const float* __restrict__ x, float* __restrict__ x1,
                       int* __restrict__ deg, float* __restrict__ accs,
                       float* __restrict__ bnacc){
  int i = blockIdx.x * 256 + threadIdx.x;
  if (i < N_*T_*LH_) x1[i] = x[i];
  if (i < NODES_) deg[i] = 0;
  if (i < 8) accs[i] = 0.f;
  if (i < 2*5*NBK_) bnacc[i] = 0.f;
}

// ---------------- degree count (includes self loops)
__global__ void k_deg(const int* __restrict__ ei, int* __restrict__ deg){
  int e = blockIdx.x * 256 + threadIdx.x;
  if (e >= EN_) return;
  int d = (e < E_) ? ei[E_ + e] : (e - E_);
  if ((unsigned)d >= NODES_) d = 0;
  atomicAdd(&deg[d], 1);
}

// ---------------- scan phase A: per-chunk totals
__global__ __launch_bounds__(256) void k_chunksum(const int* __restrict__ deg, int* __restrict__ csum){
  __shared__ int red[256];
  int chunk = blockIdx.x, tid = threadIdx.x;
  int s = 0;
  for (int i = tid; i < 1024; i += 256){
    int g = chunk*1024 + i;
    s += (g < NODES_) ? deg[g] : 0;
  }
  red[tid] = s;
  __syncthreads();
  for (int off = 128; off > 0; off >>= 1){
    if (tid < off) red[tid] += red[tid + off];
    __syncthreads();
  }
  if (tid == 0) csum[chunk] = red[0];
}

// ---------------- scan phase B: serial exclusive scan of chunk sums
__global__ void k_chunkscan(int* __restrict__ csum){
  if (threadIdx.x == 0 && blockIdx.x == 0){
    int run = 0;
    for (int i = 0; i < NCH_; i++){ int t = csum[i]; csum[i] = run; run += t; }
  }
}

// ---------------- scan phase C: intra-chunk inclusive scan -> exclusive + base; dinv
__global__ __launch_bounds__(1024) void k_scan2(const int* __restrict__ deg, const int* __restrict__ csum,
                       int* __restrict__ rowoff, int* __restrict__ wp, float* __restrict__ dinv){
  __shared__ int sdata[1024];
  int chunk = blockIdx.x, tid = threadIdx.x;
  int g = chunk*1024 + tid;
  int v = (g < NODES_) ? deg[g] : 0;
  int xv = v;
  sdata[tid] = xv;
  __syncthreads();
  for (int off = 1; off < 1024; off <<= 1){
    int add = (tid >= off) ? sdata[tid - off] : 0;
    __syncthreads();
    xv += add;
    sdata[tid] = xv;
    __syncthreads();
  }
  if (g < NODES_){
    int excl = csum[chunk] + xv - v;
    rowoff[g] = excl;
    wp[g] = excl;
    dinv[g] = (v > 0) ? rsqrtf((float)v) : 0.f;
  }
}

// ---------------- scatter edges into CSR with norm values
__global__ void k_scatter(const int* __restrict__ ei, const float* __restrict__ dinv,
                          int* __restrict__ wp, int* __restrict__ col, float* __restrict__ val){
  int e = blockIdx.x * 256 + threadIdx.x;
  if (e >= EN_) return;
  int s, d;
  if (e < E_){ s = ei[e]; d = ei[E_ + e]; } else { s = d = e - E_; }
  if ((unsigned)s >= NODES_) s = 0;
  if ((unsigned)d >= NODES_) d = 0;
  int pos = atomicAdd(&wp[d], 1);
  if ((unsigned)pos < EN_){
    col[pos] = s;
    val[pos] = dinv[s] * dinv[d];
  }
}

// ---------------- xW = x1 @ Wih + bih + bhh   (13344 x 200, K=50)
__global__ void k_xw(const float* __restrict__ x1, const float* __restrict__ Wih,
                     const float* __restrict__ bih, const float* __restrict__ bhh,
                     float* __restrict__ xW, int s){
  int idx = blockIdx.x * 256 + threadIdx.x;
  if (idx >= N_*T_*200) return;
  int r = idx / 200, g = idx % 200;
  const float* W = Wih + s*LH_*200;
  const float* xr = x1 + r*LH_;
  float acc = bih[s*200+g] + bhh[s*200+g];
  #pragma unroll 10
  for (int k = 0; k < LH_; k++) acc += xr[k] * W[k*200 + g];
  xW[idx] = acc;
}

// ---------------- LSTM recurrence (v4 structure — empirically at its latency floor)
__global__ __launch_bounds__(256, 1) void k_lstm(const float* __restrict__ xW, float* __restrict__ x1,
                       const float* __restrict__ Whh, const float* __restrict__ h0,
                       const float* __restrict__ c0, int s){
  __shared__ float hsw[4][52];       // per-wave replicated h (pad for b128)
  __shared__ float gates[2][200];    // double-buffered gate values
  __shared__ float xs[LCH_*200];     // staged xW chunk (25.6 KB)
  __shared__ float hist[LCH_*LH_];   // h history chunk (6.4 KB)
  int n = blockIdx.x, tid = threadIdx.x;
  int w = tid >> 6;
  int l = tid & 63;
  int gcol = (tid < 200) ? tid : 199;
  float wcol[LH_];
  {
    const float* W = Whh + s*LH_*200 + gcol;
    #pragma unroll
    for (int k = 0; k < LH_; k++) wcol[k] = W[k*200];
  }
  float c = 0.f;
  if (l < LH_){
    c = c0[s*N_*LH_ + n*LH_ + l];
    hsw[w][l] = h0[s*N_*LH_ + n*LH_ + l];
  }
  if (l >= LH_ && l < 52) hsw[w][l] = 0.f;
  const float* xwn = xW + (size_t)n*T_*200;
  float* out = x1 + (size_t)n*T_*LH_;
  for (int t0 = 0; t0 < T_; t0 += LCH_){
    int nst = T_ - t0; if (nst > LCH_) nst = LCH_;
    int cnt = nst*200;
    for (int idx = tid; idx < cnt; idx += 256) xs[idx] = xwn[t0*200 + idx];
    __syncthreads();   // xs ready (the once-per-chunk vmcnt drain)
    for (int i = 0; i < nst; i++){
      int t = t0 + i;
      float hreg[52];
      {
        const float4* hp = (const float4*)&hsw[w][0];
        #pragma unroll
        for (int k4 = 0; k4 < 13; k4++){
          float4 hv = hp[k4];
          hreg[k4*4]   = hv.x;
          hreg[k4*4+1] = hv.y;
          hreg[k4*4+2] = hv.z;
          hreg[k4*4+3] = hv.w;
        }
      }
      float a0 = 0.f, a1 = 0.f, a2 = 0.f, a3 = 0.f;
      #pragma unroll
      for (int k = 0; k < 48; k += 4){
        a0 += hreg[k]  *wcol[k];
        a1 += hreg[k+1]*wcol[k+1];
        a2 += hreg[k+2]*wcol[k+2];
        a3 += hreg[k+3]*wcol[k+3];
      }
      a0 += hreg[48]*wcol[48];
      a1 += hreg[49]*wcol[49];
      float acc = xs[i*200 + gcol] + ((a0 + a1) + (a2 + a3));
      if (tid < 200) gates[t & 1][tid] = acc;
      __syncthreads();   // the one barrier per step
      if (l < LH_){
        const float* gb = gates[t & 1];
        float gi = gb[l], gf = gb[LH_+l], gg = gb[100+l], go = gb[150+l];
        float si = __frcp_rn(1.f + __expf(-gi));
        float sf = __frcp_rn(1.f + __expf(-gf));
        float so = __frcp_rn(1.f + __expf(-go));
        float eg = __expf(2.f*gg);
        float tg = 1.f - 2.f*__frcp_rn(eg + 1.f);
        c = sf*c + si*tg;
        float ec = __expf(2.f*c);
        float h = so * (1.f - 2.f*__frcp_rn(ec + 1.f));
        hsw[w][l] = h;
        if (w == 0) hist[i*LH_ + l] = h;
      }
    }
    __syncthreads();  // hist complete, visible to all
    int hcnt = nst*LH_;
    for (int idx = tid; idx < hcnt; idx += 256) out[t0*LH_ + idx] = hist[idx];
  }
}

// ---------------- transpose (N,T,50) -> node-major (NODES, N, 2)
__global__ void k_tonode(const float* __restrict__ x1, float* __restrict__ P0){
  int idx = blockIdx.x * 256 + threadIdx.x;
  if (idx >= NODES_*64) return;
  int v = idx >> 6, rem = idx & 63;
  int n = rem >> 1, d = rem & 1;
  P0[idx] = x1[n*(T_*LH_) + v*D_ + d];
}

// ---------------- CSR gather + fused BN moment accumulation (bucketed atomics)
__global__ __launch_bounds__(64) void k_gather(const int* __restrict__ rowoff, const int* __restrict__ deg,
                       const int* __restrict__ col, const float* __restrict__ val,
                       const float* __restrict__ src, float* __restrict__ dst,
                       float* __restrict__ bnsum){
  int v = blockIdx.x, tid = threadIdx.x;
  int start = rowoff[v], len = deg[v];
  float acc = 0.f;
  for (int j = 0; j < len; j++){
    int cs = col[start + j];
    if ((unsigned)cs >= NODES_) cs = 0;
    acc += val[start + j] * src[cs*64 + tid];
  }
  dst[v*64 + tid] = acc;
  // moments over (v,n): lanes = (n,d) pairs; partner holds the other channel
  int d = tid & 1;
  float partner = __shfl_xor(acc, 1, 64);
  float m0  = wave_sum(d == 0 ? acc : 0.f);
  float m1  = wave_sum(d == 1 ? acc : 0.f);
  float e00 = wave_sum(d == 0 ? acc*acc : 0.f);
  float e11 = wave_sum(d == 1 ? acc*acc : 0.f);
  float e01 = wave_sum(d == 0 ? acc*partner : 0.f);
  if (tid == 0){
    int bk = blockIdx.x & (NBK_ - 1);
    atomicAdd(&bnsum[0*NBK_ + bk], m0);
    atomicAdd(&bnsum[1*NBK_ + bk], m1);
    atomicAdd(&bnsum[2*NBK_ + bk], e00);
    atomicAdd(&bnsum[3*NBK_ + bk], e11);
    atomicAdd(&bnsum[4*NBK_ + bk], e01);
  }
}

// ---------------- BN finalize: reduce buckets, per-channel scale/shift analytically
__global__ __launch_bounds__(64) void k_bnfin(const float* __restrict__ bnsum,
                        const float* __restrict__ W1, const float* __restrict__ b1,
                        const float* __restrict__ bn_g, const float* __restrict__ bn_b,
                        float* __restrict__ bnsc, int s){
  __shared__ float S[5];
  int tid = threadIdx.x;
  if (tid < 5){
    float a = 0.f;
    for (int bk = 0; bk < NBK_; bk++) a += bnsum[tid*NBK_ + bk];
    S[tid] = a;
  }
  __syncthreads();
  if (tid < HID_){
    int c = tid;
    const float M = (float)(N_*NODES_);
    float w0 = W1[s*D_*HID_ + c], w1 = W1[s*D_*HID_ + HID_ + c];
    float bc = b1[s*HID_ + c];
    float m0 = S[0]/M, m1 = S[1]/M;
    float e00 = S[2]/M, e11 = S[3]/M, e01 = S[4]/M;
    float mean = w0*m0 + w1*m1 + bc;
    float v00 = e00 - m0*m0, v11 = e11 - m1*m1, c01 = e01 - m0*m1;
    float var = w0*w0*v00 + w1*w1*v11 + 2.f*w0*w1*c01;
    var = fmaxf(var, 0.f);
    float sc = bn_g[s*HID_ + c] * rsqrtf(var + EPS_);
    bnsc[c] = sc;
    bnsc[HID_ + c] = bn_b[s*HID_ + c] - mean*sc;
  }
}

// ---------------- recompute q from P1, BN apply + relu + transform HID->D -> Rb
__global__ __launch_bounds__(256) void k_bnrelu_t2(const float* __restrict__ P1, const float* __restrict__ bnsc,
                            const float* __restrict__ W1, const float* __restrict__ b1,
                            const float* __restrict__ W2, float* __restrict__ Rb, int s){
  int idx = blockIdx.x * 256 + threadIdx.x;
  if (idx >= NODES_*N_) return;
  float p0 = P1[idx*2], p1v = P1[idx*2+1];
  const float* W1p = W1 + s*D_*HID_;
  const float* W2p = W2 + s*HID_*D_;
  float a0 = 0.f, a1 = 0.f;
  #pragma unroll
  for (int c = 0; c < HID_; c++){
    float q = p0*W1p[c] + p1v*W1p[HID_ + c] + b1[s*HID_ + c];
    float h = fmaxf(q*bnsc[c] + bnsc[HID_ + c], 0.f);
    a0 += h * W2p[c*D_];
    a1 += h * W2p[c*D_ + 1];
  }
  Rb[idx*2]     = a0;
  Rb[idx*2 + 1] = a1;
}

// ---------------- gather2 + bias, write back to (N,T,50) layout
__global__ __launch_bounds__(64) void k_gcn2(const int* __restrict__ rowoff, const int* __restrict__ deg,
                      const int* __restrict__ col, const float* __restrict__ val,
                      const float* __restrict__ Rb, const float* __restrict__ gb2,
                      float* __restrict__ x1, int s){
  int v = blockIdx.x, tid = threadIdx.x;
  int start = rowoff[v], len = deg[v];
  float acc = 0.f;
  for (int j = 0; j < len; j++){
    int cs = col[start + j];
    if ((unsigned)cs >= NODES_) cs = 0;
    acc += val[start + j] * Rb[cs*64 + tid];
  }
  int n = tid >> 1, d = tid & 1;
  x1[n*(T_*LH_) + v*D_ + d] = acc + gb2[s*D_ + d];
}

// ---------------- loss1 at sampled rows
__global__ __launch_bounds__(64) void k_loss1(const float* __restrict__ x1, const float* __restrict__ x,
                       const int* __restrict__ idx2, const float* __restrict__ fcW,
                       const float* __restrict__ fcb, float* __restrict__ accs){
  int bi = blockIdx.x;
  int n = bi / SZ_, j = bi % SZ_;
  int row = idx2[n*SZ_ + j];
  if ((unsigned)row >= (T_ - 1)) row = 0;
  int l = threadIdx.x;
  float sq = 0.f;
  if (l < LH_){
    const float* xr = x1 + n*T_*LH_ + row*LH_;
    float acc = fcb[l];
    #pragma unroll 10
    for (int k = 0; k < LH_; k++) acc += xr[k] * fcW[k*LH_ + l];
    float dd = acc - x[n*T_*LH_ + (row+1)*LH_ + l];
    sq = dd*dd;
  }
  sq = wave_sum(sq);
  if (l == 0) atomicAdd(&accs[0], sq);
}

// ---------------- conv1d (417 channels -> 85), out (N, CO, LH)
__global__ __launch_bounds__(64) void k_conv(const float* __restrict__ x1, const float* __restrict__ cW,
                      const float* __restrict__ cb, float* __restrict__ tb){
  int bi = blockIdx.x;
  int n = bi / CO_, o = bi % CO_;
  int l = threadIdx.x;
  if (l >= LH_) return;
  float acc = cb[o];
  const float* w = cW + o*T_;
  const float* xr = x1 + n*T_*LH_ + l;
  #pragma unroll 4
  for (int c2 = 0; c2 < T_; c2++) acc += w[c2] * xr[c2*LH_];
  tb[bi*LH_ + l] = acc;
}

// ---------------- fused qkv + attention per (batch-col b, head h); S=32, hd=10
__global__ __launch_bounds__(128) void k_attn(const float* __restrict__ tb,
                      const float* __restrict__ inW, const float* __restrict__ inb,
                      float* __restrict__ abuf, int l3){
  __shared__ float tin[32][LH_];
  __shared__ float qs[32][HD_], ks[32][HD_], vs[32][HD_], att[32][32];
  int bi = blockIdx.x;
  int b = bi % CO_, h = bi / CO_;
  int tid = threadIdx.x;
  // load the 32 rows this (b,*) column needs
  for (int idx = tid; idx < 32*LH_; idx += 128){
    int ss = idx / LH_, j = idx % LH_;
    tin[ss][j] = tb[(ss*CO_ + b)*LH_ + j];
  }
  __syncthreads();
  // project q/k/v for this head only (heads own disjoint weight columns)
  const float* Wl = inW + l3*LH_*150;
  for (int idx = tid; idx < 960; idx += 128){
    int grp = idx / 320, m = idx % 320, ss = m / HD_, dd = m % HD_;
    int colj = grp*LH_ + h*HD_ + dd;
    float acc = inb[l3*150 + colj];
    #pragma unroll 10
    for (int k = 0; k < LH_; k++) acc += tin[ss][k] * Wl[k*150 + colj];
    if (grp == 0) qs[ss][dd] = acc;
    else if (grp == 1) ks[ss][dd] = acc;
    else vs[ss][dd] = acc;
  }
  __syncthreads();
  const float scale = 0.31622776601683794f;  // 1/sqrt(10)
  for (int idx = tid; idx < 1024; idx += 128){
    int ss = idx >> 5, tt = idx & 31;
    float a = 0.f;
    #pragma unroll
    for (int dd = 0; dd < HD_; dd++) a += qs[ss][dd]*ks[tt][dd];
    att[ss][tt] = a*scale;
  }
  __syncthreads();
  if (tid < 32){
    float m = -1e31f;
    for (int tt = 0; tt < 32; tt++) m = fmaxf(m, att[tid][tt]);
    float sum = 0.f;
    for (int tt = 0; tt < 32; tt++){ float e = __expf(att[tid][tt] - m); att[tid][tt] = e; sum += e; }
    float inv = 1.f / fmaxf(sum, 1e-30f);
    for (int tt = 0; tt < 32; tt++) att[tid][tt] *= inv;
  }
  __syncthreads();
  for (int idx = tid; idx < 320; idx += 128){
    int ss = idx / HD_, dd = idx % HD_;
    float acc = 0.f;
    #pragma unroll
    for (int tt = 0; tt < 32; tt++) acc += att[ss][tt]*vs[tt][dd];
    abuf[(ss*CO_ + b)*LH_ + h*HD_ + dd] = acc;
  }
}

// ---------------- out-proj + residual + LN1 (row per block)
__global__ __launch_bounds__(64) void k_proj_ln(float* __restrict__ tb, const float* __restrict__ abuf,
                         const float* __restrict__ outW, const float* __restrict__ outb,
                         const float* __restrict__ g, const float* __restrict__ bb, int l3){
  __shared__ float orow[LH_];
  int r = blockIdx.x, l = threadIdx.x;
  if (l < LH_) orow[l] = abuf[r*LH_ + l];
  __syncthreads();
  float rr = 0.f;
  if (l < LH_){
    const float* W = outW + l3*LH_*LH_;
    float p = outb[l3*LH_ + l];
    #pragma unroll 10
    for (int k = 0; k < LH_; k++) p += orow[k] * W[k*LH_ + l];
    rr = tb[r*LH_ + l] + p;
  }
  float mean = wave_sum(rr) / (float)LH_;
  float dv = (l < LH_) ? (rr - mean) : 0.f;
  float var = wave_sum(dv*dv) / (float)LH_;
  if (l < LH_)
    tb[r*LH_ + l] = (rr - mean)*rsqrtf(var + EPS_)*g[l3*LH_ + l] + bb[l3*LH_ + l];
}

// ---------------- fused FFN v3: 4 rows/block, 512 thr, 8-way split GEMM2 + LN2
__global__ __launch_bounds__(512) void k_ff(float* __restrict__ tb, const float* __restrict__ w1,
                     const float* __restrict__ bi1, const float* __restrict__ w2,
                     const float* __restrict__ bi2, const float* __restrict__ g,
                     const float* __restrict__ bb, int l3){
  __shared__ float tin[4][LH_];
  __shared__ float hb[4][FF_];
  __shared__ float part[4][8][LH_];
  int r0 = blockIdx.x * 4, tid = threadIdx.x;
  if (tid < 4*LH_) tin[tid/LH_][tid%LH_] = tb[r0*LH_ + tid];
  __syncthreads();
  const float* W1l = w1 + l3*LH_*FF_;
  #pragma unroll
  for (int i = 0; i < 4; i++){
    int j = i*512 + tid;
    float bj = bi1[l3*FF_ + j];
    float a0 = bj, a1 = bj, a2 = bj, a3 = bj;
    #pragma unroll 10
    for (int k = 0; k < LH_; k++){
      float w = W1l[k*FF_ + j];
      a0 += tin[0][k]*w;
      a1 += tin[1][k]*w;
      a2 += tin[2][k]*w;
      a3 += tin[3][k]*w;
    }
    hb[0][j] = fmaxf(a0, 0.f);
    hb[1][j] = fmaxf(a1, 0.f);
    hb[2][j] = fmaxf(a2, 0.f);
    hb[3][j] = fmaxf(a3, 0.f);
  }
  __syncthreads();
  const float* W2l = w2 + l3*FF_*LH_;
  int l = tid & 63, grp = tid >> 6;
  if (l < LH_){
    float a0 = 0.f, a1 = 0.f, a2 = 0.f, a3 = 0.f;
    int jbase = grp * 256;
    const float* wp = W2l + (size_t)jbase*LH_ + l;
    for (int jj = 0; jj < 256; jj++){
      float w = wp[jj*LH_];
      a0 += hb[0][jbase + jj]*w;
      a1 += hb[1][jbase + jj]*w;
      a2 += hb[2][jbase + jj]*w;
      a3 += hb[3][jbase + jj]*w;
    }
    part[0][grp][l] = a0;
    part[1][grp][l] = a1;
    part[2][grp][l] = a2;
    part[3][grp][l] = a3;
  }
  __syncthreads();
  if (tid < 256){
    int row = tid >> 6, ll = tid & 63;
    float out = 0.f;
    if (ll < LH_){
      float a = 0.f;
      #pragma unroll
      for (int gg = 0; gg < 8; gg++) a += part[row][gg][ll];
      out = a + bi2[l3*LH_ + ll] + tin[row][ll];
    }
    float s1 = (ll < LH_) ? out : 0.f;
    float mean = wave_sum(s1) / (float)LH_;
    float dv = (ll < LH_) ? (out - mean) : 0.f;
    float var = wave_sum(dv*dv) / (float)LH_;
    if (ll < LH_)
      tb[(r0 + row)*LH_ + ll] = (out - mean)*rsqrtf(var + EPS_)*g[l3*LH_ + ll] + bb[l3*LH_ + ll];
  }
}

// ---------------- classifier head v2: 512 thr, 8-way k-split for the 4250-dot
__global__ __launch_bounds__(512) void k_head(const float* __restrict__ tb, const int* __restrict__ y,
                       const float* __restrict__ Wc1, const float* __restrict__ bc1,
                       const float* __restrict__ Wc2, const float* __restrict__ bc2,
                       float* __restrict__ out, float* __restrict__ accs){
  __shared__ float part[8][LH_];
  __shared__ float h1[LH_];
  __shared__ float lgs[NC_];
  int n = blockIdx.x, tid = threadIdx.x;
  int l = tid & 63, grp = tid >> 6;
  const float* tr = tb + n*CO_*LH_;
  if (l < LH_){
    int k0 = grp * 532;
    int k1 = k0 + 532; if (k1 > CO_*LH_) k1 = CO_*LH_;
    float acc = 0.f;
    for (int k = k0; k < k1; k++) acc += tr[k] * Wc1[k*LH_ + l];
    part[grp][l] = acc;
  }
  __syncthreads();
  if (tid < LH_){
    float a = bc1[tid];
    #pragma unroll
    for (int gg = 0; gg < 8; gg++) a += part[gg][tid];
    h1[tid] = fmaxf(a, 0.f);
  }
  __syncthreads();
  if (tid < NC_){
    float a = bc2[tid];
    #pragma unroll 10
    for (int k = 0; k < LH_; k++) a += h1[k] * Wc2[k*NC_ + tid];
    lgs[tid] = a;
  }
  __syncthreads();
  if (tid == 0){
    float m = -1e31f;
    for (int c2 = 0; c2 < NC_; c2++) m = fmaxf(m, lgs[c2]);
    float sum = 0.f;
    for (int c2 = 0; c2 < NC_; c2++) sum += __expf(lgs[c2] - m);
    float lse = m + logf(fmaxf(sum, 1e-30f));
    for (int c2 = 0; c2 < NC_; c2++)
      out[n*NC_ + c2] = __expf(lgs[c2] - lse);
    int yy = y[n];
    if ((unsigned)yy >= NC_) yy = 0;
    atomicAdd(&accs[1], -(lgs[yy] - lse));
  }
}

// ---------------- finalize losses
__global__ void k_fin(const float* __restrict__ accs, float* __restrict__ out){
  if (threadIdx.x == 0 && blockIdx.x == 0){
    out[N_*NC_]     = sane(accs[0] / (float)(N_*SZ_*LH_));
    out[N_*NC_ + 1] = sane(accs[1] / (float)N_);
  }
}

extern "C" void kernel_launch(void* const* d_in, const int* in_sizes, int n_in,
                              void* d_out, int out_size, void* d_ws, size_t ws_size,
                              hipStream_t stream){
  // ---- interface validation beacon: on ANY mismatch, launch nothing
  static const int expect[36] = {
    667200, 32, 160000, 2656, 3200, 3200,
    20000, 20000, 400, 400,
    80, 40, 40, 40, 80, 4,
    2500, 50, 35445, 85,
    22500, 450, 7500, 150,
    307200, 6144, 307200, 150,
    150, 150, 150, 150,
    212500, 50, 300, 6
  };
  if (n_in != 36 || out_size != 194 || ws_size < 14300000) return;
  for (int i = 0; i < 36; i++) if (in_sizes[i] != expect[i]) return;

  const float* x        = (const float*)d_in[0];
  const int*   y        = (const int*)d_in[1];
  const int*   ei       = (const int*)d_in[2];
  const int*   idx2     = (const int*)d_in[3];
  const float* h0s      = (const float*)d_in[4];
  const float* c0s      = (const float*)d_in[5];
  const float* lstm_Wih = (const float*)d_in[6];
  const float* lstm_Whh = (const float*)d_in[7];
  const float* lstm_bih = (const float*)d_in[8];
  const float* lstm_bhh = (const float*)d_in[9];
  const float* gcn1_W   = (const float*)d_in[10];
  const float* gcn1_b   = (const float*)d_in[11];
  const float* bn_g     = (const float*)d_in[12];
  const float* bn_b     = (const float*)d_in[13];
  const float* gcn2_W   = (const float*)d_in[14];
  const float* gcn2_b   = (const float*)d_in[15];
  const float* fc_W     = (const float*)d_in[16];
  const float* fc_b     = (const float*)d_in[17];
  const float* conv_W   = (const float*)d_in[18];
  const float* conv_b   = (const float*)d_in[19];
  const float* attn_inW = (const float*)d_in[20];
  const float* attn_inb = (const float*)d_in[21];
  const float* attn_outW= (const float*)d_in[22];
  const float* attn_outb= (const float*)d_in[23];
  const float* ff1W     = (const float*)d_in[24];
  const float* ff1b     = (const float*)d_in[25];
  const float* ff2W     = (const float*)d_in[26];
  const float* ff2b     = (const float*)d_in[27];
  const float* ln1g     = (const float*)d_in[28];
  const float* ln1b     = (const float*)d_in[29];
  const float* ln2g     = (const float*)d_in[30];
  const float* ln2b     = (const float*)d_in[31];
  const float* Wc1      = (const float*)d_in[32];
  const float* bc1      = (const float*)d_in[33];
  const float* Wc2      = (const float*)d_in[34];
  const float* bc2      = (const float*)d_in[35];
  float* out = (float*)d_out;

  // ---- workspace layout (~14.25 MB; big region X is reused across phases)
  char* wsp = (char*)d_ws;
  size_t off = 0;
  auto alloc = [&](size_t bytes)->void*{
    void* p = wsp + off;
    off = (off + bytes + 255) & ~(size_t)255;
    return p;
  };
  float* x1   = (float*)alloc((size_t)N_*T_*LH_*4);       // 2.67 MB, persistent
  float* X    = (float*)alloc((size_t)N_*T_*200*4);       // 10.7 MB region, multi-use
  float* val  = (float*)alloc((size_t)EN_*4);
  float* dinv = (float*)alloc((size_t)NODES_*4);
  float* bnsc = (float*)alloc(64*4);
  float* accs = (float*)alloc(8*4);
  float* bnacc= (float*)alloc((size_t)2*5*NBK_*4);        // moment buckets, 2 stages
  int*   deg  = (int*)alloc((size_t)NODES_*4);
  int*   rowoff = (int*)alloc((size_t)(NODES_+1)*4);
  int*   wp   = (int*)alloc((size_t)NODES_*4);
  int*   col  = (int*)alloc((size_t)EN_*4);
  int*   csum = (int*)alloc(16*4);
  float* xW     = X;
  float* P0     = X;
  float* P1     = X + (size_t)NODES_*64;
  float* Rb     = P0;
  float* tb     = X;                                  // 136000 f
  float* abuf   = X + 136064;                         // 136000 f

  k_init<<<dim3((N_*T_*LH_ + 255)/256), dim3(256), 0, stream>>>(x, x1, deg, accs, bnacc);
  k_deg<<<dim3((EN_ + 255)/256), dim3(256), 0, stream>>>(ei, deg);
  k_chunksum<<<dim3(NCH_), dim3(256), 0, stream>>>(deg, csum);
  k_chunkscan<<<dim3(1), dim3(64), 0, stream>>>(csum);
  k_scan2<<<dim3(NCH_), dim3(1024), 0, stream>>>(deg, csum, rowoff, wp, dinv);
  k_scatter<<<dim3((EN_ + 255)/256), dim3(256), 0, stream>>>(ei, dinv, wp, col, val);

  for (int s = 0; s < NS_; s++){
    k_xw<<<dim3((N_*T_*200 + 255)/256), dim3(256), 0, stream>>>(x1, lstm_Wih, lstm_bih, lstm_bhh, xW, s);
    k_lstm<<<dim3(N_), dim3(256), 0, stream>>>(xW, x1, lstm_Whh, h0s, c0s, s);
    k_tonode<<<dim3((NODES_*64 + 255)/256), dim3(256), 0, stream>>>(x1, P0);
    k_gather<<<dim3(NODES_), dim3(64), 0, stream>>>(rowoff, deg, col, val, P0, P1, bnacc + s*5*NBK_);
    k_bnfin<<<dim3(1), dim3(64), 0, stream>>>(bnacc + s*5*NBK_, gcn1_W, gcn1_b, bn_g, bn_b, bnsc, s);
    k_bnrelu_t2<<<dim3((N_*NODES_ + 255)/256), dim3(256), 0, stream>>>(P1, bnsc, gcn1_W, gcn1_b, gcn2_W, Rb, s);
    k_gcn2<<<dim3(NODES_), dim3(64), 0, stream>>>(rowoff, deg, col, val, Rb, gcn2_b, x1, s);
  }

  k_loss1<<<dim3(N_*SZ_), dim3(64), 0, stream>>>(x1, x, idx2, fc_W, fc_b, accs);
  k_conv<<<dim3(N_*CO_), dim3(64), 0, stream>>>(x1, conv_W, conv_b, tb);

  for (int l3 = 0; l3 < NL_; l3++){
    k_attn<<<dim3(NH_*CO_), dim3(128), 0, stream>>>(tb, attn_inW, attn_inb, abuf, l3);
    k_proj_ln<<<dim3(N_*CO_), dim3(64), 0, stream>>>(tb, abuf, attn_outW, attn_outb, ln1g, ln1b, l3);
    k_ff<<<dim3(N_*CO_/4), dim3(512), 0, stream>>>(tb, ff1W, ff1b, ff2W, ff2b, ln2g, ln2b, l3);
  }

  k_head<<<dim3(N_), dim3(512), 0, stream>>>(tb, y, Wc1, bc1, Wc2, bc2, out, accs);
  k_fin<<<dim3(1), dim3(64), 0, stream>>>(accs, out);
}

// Round 14
// 1345.699 us; speedup vs baseline: 1.0761x; 1.0761x over previous
//
#include <hip/hip_runtime.h>
#include <math.h>

#define N_ 32
#define T_ 417
#define V_ 25
#define D_ 2
#define NODES_ 10425          // T_*V_
#define E_ 80000
#define EN_ (E_ + NODES_)     // 90425 (edges + self loops)
#define HID_ 20
#define LH_ 50
#define NH_ 5
#define HD_ 10
#define FF_ 2048
#define NL_ 3
#define CO_ 85
#define NC_ 6
#define NS_ 2
#define SZ_ 83
#define EPS_ 1e-5f
#define NCH_ 11               // scan chunks of 1024 covering NODES_
#define NBNB_ 1304            // ceil(NODES_*N_ / 256) blocks for bn stats
#define LCH_ 32               // LSTM steps staged per LDS chunk

__device__ inline float sane(float v){
  return (v == v && fabsf(v) < 1e30f) ? v : 0.f;
}

__device__ inline float wave_sum(float v){
  #pragma unroll
  for (int off = 32; off > 0; off >>= 1) v += __shfl_xor(v, off, 64);
  return v;
}

// ---------------- init: copy x -> x1, zero deg + loss accumulators
__global__ void k_init(const float* __restrict__ x, float* __restrict__ x1,
                       int* __restrict__ deg, float* __restrict__ accs){
  int i = blockIdx.x * 256 + threadIdx.x;
  if (i < N_*T_*LH_) x1[i] = x[i];
  if (i < NODES_) deg[i] = 0;
  if (i < 8) accs[i] = 0.f;
}

// ---------------- degree count (includes self loops)
__global__ void k_deg(const int* __restrict__ ei, int* __restrict__ deg){
  int e = blockIdx.x * 256 + threadIdx.x;
  if (e >= EN_) return;
  int d = (e < E_) ? ei[E_ + e] : (e - E_);
  if ((unsigned)d >= NODES_) d = 0;
  atomicAdd(&deg[d], 1);
}

// ---------------- scan phase A: per-chunk totals
__global__ __launch_bounds__(256) void k_chunksum(const int* __restrict__ deg, int* __restrict__ csum){
  __shared__ int red[256];
  int chunk = blockIdx.x, tid = threadIdx.x;
  int s = 0;
  for (int i = tid; i < 1024; i += 256){
    int g = chunk*1024 + i;
    s += (g < NODES_) ? deg[g] : 0;
  }
  red[tid] = s;
  __syncthreads();
  for (int off = 128; off > 0; off >>= 1){
    if (tid < off) red[tid] += red[tid + off];
    __syncthreads();
  }
  if (tid == 0) csum[chunk] = red[0];
}

// ---------------- scan phase B: serial exclusive scan of chunk sums
__global__ void k_chunkscan(int* __restrict__ csum){
  if (threadIdx.x == 0 && blockIdx.x == 0){
    int run = 0;
    for (int i = 0; i < NCH_; i++){ int t = csum[i]; csum[i] = run; run += t; }
  }
}

// ---------------- scan phase C: intra-chunk inclusive scan -> exclusive + base; dinv
__global__ __launch_bounds__(1024) void k_scan2(const int* __restrict__ deg, const int* __restrict__ csum,
                       int* __restrict__ rowoff, int* __restrict__ wp, float* __restrict__ dinv){
  __shared__ int sdata[1024];
  int chunk = blockIdx.x, tid = threadIdx.x;
  int g = chunk*1024 + tid;
  int v = (g < NODES_) ? deg[g] : 0;
  int xv = v;
  sdata[tid] = xv;
  __syncthreads();
  for (int off = 1; off < 1024; off <<= 1){
    int add = (tid >= off) ? sdata[tid - off] : 0;
    __syncthreads();
    xv += add;
    sdata[tid] = xv;
    __syncthreads();
  }
  if (g < NODES_){
    int excl = csum[chunk] + xv - v;
    rowoff[g] = excl;
    wp[g] = excl;
    dinv[g] = (v > 0) ? rsqrtf((float)v) : 0.f;
  }
}

// ---------------- scatter edges into CSR with norm values
__global__ void k_scatter(const int* __restrict__ ei, const float* __restrict__ dinv,
                          int* __restrict__ wp, int* __restrict__ col, float* __restrict__ val){
  int e = blockIdx.x * 256 + threadIdx.x;
  if (e >= EN_) return;
  int s, d;
  if (e < E_){ s = ei[e]; d = ei[E_ + e]; } else { s = d = e - E_; }
  if ((unsigned)s >= NODES_) s = 0;
  if ((unsigned)d >= NODES_) d = 0;
  int pos = atomicAdd(&wp[d], 1);
  if ((unsigned)pos < EN_){
    col[pos] = s;
    val[pos] = dinv[s] * dinv[d];
  }
}

// ---------------- xW = x1 @ Wih + bih + bhh   (13344 x 200, K=50)
__global__ void k_xw(const float* __restrict__ x1, const float* __restrict__ Wih,
                     const float* __restrict__ bih, const float* __restrict__ bhh,
                     float* __restrict__ xW, int s){
  int idx = blockIdx.x * 256 + threadIdx.x;
  if (idx >= N_*T_*200) return;
  int r = idx / 200, g = idx % 200;
  const float* W = Wih + s*LH_*200;
  const float* xr = x1 + r*LH_;
  float acc = bih[s*200+g] + bhh[s*200+g];
  #pragma unroll 10
  for (int k = 0; k < LH_; k++) acc += xr[k] * W[k*200 + g];
  xW[idx] = acc;
}

// ---------------- LSTM recurrence (v4 structure — empirically at its latency floor)
__global__ __launch_bounds__(256, 1) void k_lstm(const float* __restrict__ xW, float* __restrict__ x1,
                       const float* __restrict__ Whh, const float* __restrict__ h0,
                       const float* __restrict__ c0, int s){
  __shared__ float hsw[4][52];       // per-wave replicated h (pad for b128)
  __shared__ float gates[2][200];    // double-buffered gate values
  __shared__ float xs[LCH_*200];     // staged xW chunk (25.6 KB)
  __shared__ float hist[LCH_*LH_];   // h history chunk (6.4 KB)
  int n = blockIdx.x, tid = threadIdx.x;
  int w = tid >> 6;
  int l = tid & 63;
  int gcol = (tid < 200) ? tid : 199;
  float wcol[LH_];
  {
    const float* W = Whh + s*LH_*200 + gcol;
    #pragma unroll
    for (int k = 0; k < LH_; k++) wcol[k] = W[k*200];
  }
  float c = 0.f;
  if (l < LH_){
    c = c0[s*N_*LH_ + n*LH_ + l];
    hsw[w][l] = h0[s*N_*LH_ + n*LH_ + l];
  }
  if (l >= LH_ && l < 52) hsw[w][l] = 0.f;
  const float* xwn = xW + (size_t)n*T_*200;
  float* out = x1 + (size_t)n*T_*LH_;
  for (int t0 = 0; t0 < T_; t0 += LCH_){
    int nst = T_ - t0; if (nst > LCH_) nst = LCH_;
    int cnt = nst*200;
    for (int idx = tid; idx < cnt; idx += 256) xs[idx] = xwn[t0*200 + idx];
    __syncthreads();   // xs ready (the once-per-chunk vmcnt drain)
    for (int i = 0; i < nst; i++){
      int t = t0 + i;
      float hreg[52];
      {
        const float4* hp = (const float4*)&hsw[w][0];
        #pragma unroll
        for (int k4 = 0; k4 < 13; k4++){
          float4 hv = hp[k4];
          hreg[k4*4]   = hv.x;
          hreg[k4*4+1] = hv.y;
          hreg[k4*4+2] = hv.z;
          hreg[k4*4+3] = hv.w;
        }
      }
      float a0 = 0.f, a1 = 0.f, a2 = 0.f, a3 = 0.f;
      #pragma unroll
      for (int k = 0; k < 48; k += 4){
        a0 += hreg[k]  *wcol[k];
        a1 += hreg[k+1]*wcol[k+1];
        a2 += hreg[k+2]*wcol[k+2];
        a3 += hreg[k+3]*wcol[k+3];
      }
      a0 += hreg[48]*wcol[48];
      a1 += hreg[49]*wcol[49];
      float acc = xs[i*200 + gcol] + ((a0 + a1) + (a2 + a3));
      if (tid < 200) gates[t & 1][tid] = acc;
      __syncthreads();   // the one barrier per step
      if (l < LH_){
        const float* gb = gates[t & 1];
        float gi = gb[l], gf = gb[LH_+l], gg = gb[100+l], go = gb[150+l];
        float si = __frcp_rn(1.f + __expf(-gi));
        float sf = __frcp_rn(1.f + __expf(-gf));
        float so = __frcp_rn(1.f + __expf(-go));
        float eg = __expf(2.f*gg);
        float tg = 1.f - 2.f*__frcp_rn(eg + 1.f);
        c = sf*c + si*tg;
        float ec = __expf(2.f*c);
        float h = so * (1.f - 2.f*__frcp_rn(ec + 1.f));
        hsw[w][l] = h;
        if (w == 0) hist[i*LH_ + l] = h;
      }
    }
    __syncthreads();  // hist complete, visible to all
    int hcnt = nst*LH_;
    for (int idx = tid; idx < hcnt; idx += 256) out[t0*LH_ + idx] = hist[idx];
  }
}

// ---------------- transpose (N,T,50) -> node-major (NODES, N, 2)
__global__ void k_tonode(const float* __restrict__ x1, float* __restrict__ P0){
  int idx = blockIdx.x * 256 + threadIdx.x;
  if (idx >= NODES_*64) return;
  int v = idx >> 6, rem = idx & 63;
  int n = rem >> 1, d = rem & 1;
  P0[idx] = x1[n*(T_*LH_) + v*D_ + d];
}

// ---------------- CSR gather: dst[v][*] = sum_nbr val * src[col][*]
__global__ __launch_bounds__(64) void k_gather(const int* __restrict__ rowoff, const int* __restrict__ deg,
                       const int* __restrict__ col, const float* __restrict__ val,
                       const float* __restrict__ src, float* __restrict__ dst){
  int v = blockIdx.x, tid = threadIdx.x;
  int start = rowoff[v], len = deg[v];
  float acc = 0.f;
  for (int j = 0; j < len; j++){
    int cs = col[start + j];
    if ((unsigned)cs >= NODES_) cs = 0;
    acc += val[start + j] * src[cs*64 + tid];
  }
  dst[v*64 + tid] = acc;
}

// ---------------- BN moment partials over P1: {p0, p1, p0^2, p1^2, p0*p1}
__global__ __launch_bounds__(256) void k_bnstat(const float* __restrict__ P1, float* __restrict__ bnpart){
  int idx = blockIdx.x * 256 + threadIdx.x;   // over (v,n)
  float p0 = 0.f, p1v = 0.f;
  if (idx < NODES_*N_){ p0 = P1[idx*2]; p1v = P1[idx*2+1]; }
  float sv[5] = {p0, p1v, p0*p0, p1v*p1v, p0*p1v};
  __shared__ float red[5][4];
  int wave = threadIdx.x >> 6, lane = threadIdx.x & 63;
  #pragma unroll
  for (int j = 0; j < 5; j++){
    float w = wave_sum(sv[j]);
    if (lane == 0) red[j][wave] = w;
  }
  __syncthreads();
  if (threadIdx.x < 5){
    int j = threadIdx.x;
    bnpart[j*NBNB_ + blockIdx.x] = red[j][0] + red[j][1] + red[j][2] + red[j][3];
  }
}

// ---------------- BN finalize: reduce partials, per-channel scale/shift analytically
__global__ __launch_bounds__(256) void k_bnfin(const float* __restrict__ bnpart,
                        const float* __restrict__ W1, const float* __restrict__ b1,
                        const float* __restrict__ bn_g, const float* __restrict__ bn_b,
                        float* __restrict__ bnsc, int s){
  __shared__ float red[256];
  __shared__ float S[5];
  int tid = threadIdx.x;
  for (int j = 0; j < 5; j++){
    float acc = 0.f;
    for (int t = tid; t < NBNB_; t += 256) acc += bnpart[j*NBNB_ + t];
    red[tid] = acc;
    __syncthreads();
    for (int off = 128; off > 0; off >>= 1){
      if (tid < off) red[tid] += red[tid + off];
      __syncthreads();
    }
    if (tid == 0) S[j] = red[0];
    __syncthreads();
  }
  if (tid < HID_){
    int c = tid;
    const float M = (float)(N_*NODES_);
    float w0 = W1[s*D_*HID_ + c], w1 = W1[s*D_*HID_ + HID_ + c];
    float bc = b1[s*HID_ + c];
    float m0 = S[0]/M, m1 = S[1]/M;
    float e00 = S[2]/M, e11 = S[3]/M, e01 = S[4]/M;
    float mean = w0*m0 + w1*m1 + bc;
    float v00 = e00 - m0*m0, v11 = e11 - m1*m1, c01 = e01 - m0*m1;
    float var = w0*w0*v00 + w1*w1*v11 + 2.f*w0*w1*c01;
    var = fmaxf(var, 0.f);
    float sc = bn_g[s*HID_ + c] * rsqrtf(var + EPS_);
    bnsc[c] = sc;
    bnsc[HID_ + c] = bn_b[s*HID_ + c] - mean*sc;
  }
}

// ---------------- recompute q from P1, BN apply + relu + transform HID->D -> Rb
__global__ __launch_bounds__(256) void k_bnrelu_t2(const float* __restrict__ P1, const float* __restrict__ bnsc,
                            const float* __restrict__ W1, const float* __restrict__ b1,
                            const float* __restrict__ W2, float* __restrict__ Rb, int s){
  int idx = blockIdx.x * 256 + threadIdx.x;
  if (idx >= NODES_*N_) return;
  float p0 = P1[idx*2], p1v = P1[idx*2+1];
  const float* W1p = W1 + s*D_*HID_;
  const float* W2p = W2 + s*HID_*D_;
  float a0 = 0.f, a1 = 0.f;
  #pragma unroll
  for (int c = 0; c < HID_; c++){
    float q = p0*W1p[c] + p1v*W1p[HID_ + c] + b1[s*HID_ + c];
    float h = fmaxf(q*bnsc[c] + bnsc[HID_ + c], 0.f);
    a0 += h * W2p[c*D_];
    a1 += h * W2p[c*D_ + 1];
  }
  Rb[idx*2]     = a0;
  Rb[idx*2 + 1] = a1;
}

// ---------------- gather2 + bias, write back to (N,T,50) layout
__global__ __launch_bounds__(64) void k_gcn2(const int* __restrict__ rowoff, const int* __restrict__ deg,
                      const int* __restrict__ col, const float* __restrict__ val,
                      const float* __restrict__ Rb, const float* __restrict__ gb2,
                      float* __restrict__ x1, int s){
  int v = blockIdx.x, tid = threadIdx.x;
  int start = rowoff[v], len = deg[v];
  float acc = 0.f;
  for (int j = 0; j < len; j++){
    int cs = col[start + j];
    if ((unsigned)cs >= NODES_) cs = 0;
    acc += val[start + j] * Rb[cs*64 + tid];
  }
  int n = tid >> 1, d = tid & 1;
  x1[n*(T_*LH_) + v*D_ + d] = acc + gb2[s*D_ + d];
}

// ---------------- loss1 at sampled rows
__global__ __launch_bounds__(64) void k_loss1(const float* __restrict__ x1, const float* __restrict__ x,
                       const int* __restrict__ idx2, const float* __restrict__ fcW,
                       const float* __restrict__ fcb, float* __restrict__ accs){
  int bi = blockIdx.x;
  int n = bi / SZ_, j = bi % SZ_;
  int row = idx2[n*SZ_ + j];
  if ((unsigned)row >= (T_ - 1)) row = 0;
  int l = threadIdx.x;
  float sq = 0.f;
  if (l < LH_){
    const float* xr = x1 + n*T_*LH_ + row*LH_;
    float acc = fcb[l];
    #pragma unroll 10
    for (int k = 0; k < LH_; k++) acc += xr[k] * fcW[k*LH_ + l];
    float dd = acc - x[n*T_*LH_ + (row+1)*LH_ + l];
    sq = dd*dd;
  }
  sq = wave_sum(sq);
  if (l == 0) atomicAdd(&accs[0], sq);
}

// ---------------- conv1d (417 channels -> 85), out (N, CO, LH)
__global__ __launch_bounds__(64) void k_conv(const float* __restrict__ x1, const float* __restrict__ cW,
                      const float* __restrict__ cb, float* __restrict__ tb){
  int bi = blockIdx.x;
  int n = bi / CO_, o = bi % CO_;
  int l = threadIdx.x;
  if (l >= LH_) return;
  float acc = cb[o];
  const float* w = cW + o*T_;
  const float* xr = x1 + n*T_*LH_ + l;
  #pragma unroll 4
  for (int c2 = 0; c2 < T_; c2++) acc += w[c2] * xr[c2*LH_];
  tb[bi*LH_ + l] = acc;
}

// ---------------- qkv projection
__global__ void k_qkv(const float* __restrict__ tb, const float* __restrict__ inW,
                      const float* __restrict__ inb, float* __restrict__ qkv, int l3){
  int idx = blockIdx.x * 256 + threadIdx.x;
  if (idx >= N_*CO_*150) return;
  int r = idx / 150, j = idx % 150;
  const float* W = inW + l3*LH_*150;
  const float* tr = tb + r*LH_;
  float acc = inb[l3*150 + j];
  #pragma unroll 10
  for (int k = 0; k < LH_; k++) acc += tr[k] * W[k*150 + j];
  qkv[idx] = acc;
}

// ---------------- attention per (batch-col b, head h); S=32, hd=10
__global__ __launch_bounds__(128) void k_attn(const float* __restrict__ qkv, float* __restrict__ abuf){
  __shared__ float qs[32][HD_], ks[32][HD_], vs[32][HD_], att[32][32];
  int bi = blockIdx.x;
  int b = bi % CO_, h = bi / CO_;
  int tid = threadIdx.x;
  for (int idx = tid; idx < 960; idx += 128){
    int grp = idx / 320, m = idx % 320, ss = m / HD_, dd = m % HD_;
    float vvv = qkv[(ss*CO_ + b)*150 + grp*LH_ + h*HD_ + dd];
    if (grp == 0) qs[ss][dd] = vvv;
    else if (grp == 1) ks[ss][dd] = vvv;
    else vs[ss][dd] = vvv;
  }
  __syncthreads();
  const float scale = 0.31622776601683794f;  // 1/sqrt(10)
  for (int idx = tid; idx < 1024; idx += 128){
    int ss = idx >> 5, tt = idx & 31;
    float a = 0.f;
    #pragma unroll
    for (int dd = 0; dd < HD_; dd++) a += qs[ss][dd]*ks[tt][dd];
    att[ss][tt] = a*scale;
  }
  __syncthreads();
  if (tid < 32){
    float m = -1e31f;
    for (int tt = 0; tt < 32; tt++) m = fmaxf(m, att[tid][tt]);
    float sum = 0.f;
    for (int tt = 0; tt < 32; tt++){ float e = __expf(att[tid][tt] - m); att[tid][tt] = e; sum += e; }
    float inv = 1.f / fmaxf(sum, 1e-30f);
    for (int tt = 0; tt < 32; tt++) att[tid][tt] *= inv;
  }
  __syncthreads();
  for (int idx = tid; idx < 320; idx += 128){
    int ss = idx / HD_, dd = idx % HD_;
    float acc = 0.f;
    #pragma unroll
    for (int tt = 0; tt < 32; tt++) acc += att[ss][tt]*vs[tt][dd];
    abuf[(ss*CO_ + b)*LH_ + h*HD_ + dd] = acc;
  }
}

// ---------------- out-proj + residual + LN1 (row per block)
__global__ __launch_bounds__(64) void k_proj_ln(float* __restrict__ tb, const float* __restrict__ abuf,
                         const float* __restrict__ outW, const float* __restrict__ outb,
                         const float* __restrict__ g, const float* __restrict__ bb, int l3){
  __shared__ float orow[LH_];
  int r = blockIdx.x, l = threadIdx.x;
  if (l < LH_) orow[l] = abuf[r*LH_ + l];
  __syncthreads();
  float rr = 0.f;
  if (l < LH_){
    const float* W = outW + l3*LH_*LH_;
    float p = outb[l3*LH_ + l];
    #pragma unroll 10
    for (int k = 0; k < LH_; k++) p += orow[k] * W[k*LH_ + l];
    rr = tb[r*LH_ + l] + p;
  }
  float mean = wave_sum(rr) / (float)LH_;
  float dv = (l < LH_) ? (rr - mean) : 0.f;
  float var = wave_sum(dv*dv) / (float)LH_;
  if (l < LH_)
    tb[r*LH_ + l] = (rr - mean)*rsqrtf(var + EPS_)*g[l3*LH_ + l] + bb[l3*LH_ + l];
}

// ---------------- fused FFN v3: 4 rows/block (halves W1/W2 L2 re-reads), 512 thr
// grid = N_*CO_/4 = 680 ; LDS ~40 KB -> 4 blocks/CU
__global__ __launch_bounds__(512) void k_ff(float* __restrict__ tb, const float* __restrict__ w1,
                     const float* __restrict__ bi1, const float* __restrict__ w2,
                     const float* __restrict__ bi2, const float* __restrict__ g,
                     const float* __restrict__ bb, int l3){
  __shared__ float tin[4][LH_];
  __shared__ float hb[4][FF_];
  __shared__ float part[4][8][LH_];
  int r0 = blockIdx.x * 4, tid = threadIdx.x;
  if (tid < 4*LH_) tin[tid/LH_][tid%LH_] = tb[r0*LH_ + tid];
  __syncthreads();
  const float* W1l = w1 + l3*LH_*FF_;
  #pragma unroll
  for (int i = 0; i < 4; i++){
    int j = i*512 + tid;
    float bj = bi1[l3*FF_ + j];
    float a0 = bj, a1 = bj, a2 = bj, a3 = bj;
    #pragma unroll 10
    for (int k = 0; k < LH_; k++){
      float w = W1l[k*FF_ + j];
      a0 += tin[0][k]*w;
      a1 += tin[1][k]*w;
      a2 += tin[2][k]*w;
      a3 += tin[3][k]*w;
    }
    hb[0][j] = fmaxf(a0, 0.f);
    hb[1][j] = fmaxf(a1, 0.f);
    hb[2][j] = fmaxf(a2, 0.f);
    hb[3][j] = fmaxf(a3, 0.f);
  }
  __syncthreads();
  const float* W2l = w2 + l3*FF_*LH_;
  int l = tid & 63, grp = tid >> 6;
  if (l < LH_){
    float a0 = 0.f, a1 = 0.f, a2 = 0.f, a3 = 0.f;
    int jbase = grp * 256;
    const float* wp = W2l + (size_t)jbase*LH_ + l;
    for (int jj = 0; jj < 256; jj++){
      float w = wp[jj*LH_];
      a0 += hb[0][jbase + jj]*w;
      a1 += hb[1][jbase + jj]*w;
      a2 += hb[2][jbase + jj]*w;
      a3 += hb[3][jbase + jj]*w;
    }
    part[0][grp][l] = a0;
    part[1][grp][l] = a1;
    part[2][grp][l] = a2;
    part[3][grp][l] = a3;
  }
  __syncthreads();
  if (tid < 256){
    int row = tid >> 6, ll = tid & 63;
    float out = 0.f;
    if (ll < LH_){
      float a = 0.f;
      #pragma unroll
      for (int gg = 0; gg < 8; gg++) a += part[row][gg][ll];
      out = a + bi2[l3*LH_ + ll] + tin[row][ll];
    }
    float s1 = (ll < LH_) ? out : 0.f;
    float mean = wave_sum(s1) / (float)LH_;
    float dv = (ll < LH_) ? (out - mean) : 0.f;
    float var = wave_sum(dv*dv) / (float)LH_;
    if (ll < LH_)
      tb[(r0 + row)*LH_ + ll] = (out - mean)*rsqrtf(var + EPS_)*g[l3*LH_ + ll] + bb[l3*LH_ + ll];
  }
}

// ---------------- classifier head v2: 512 thr, 8-way k-split for the 4250-dot
__global__ __launch_bounds__(512) void k_head(const float* __restrict__ tb, const int* __restrict__ y,
                       const float* __restrict__ Wc1, const float* __restrict__ bc1,
                       const float* __restrict__ Wc2, const float* __restrict__ bc2,
                       float* __restrict__ out, float* __restrict__ accs){
  __shared__ float part[8][LH_];
  __shared__ float h1[LH_];
  __shared__ float lgs[NC_];
  int n = blockIdx.x, tid = threadIdx.x;
  int l = tid & 63, grp = tid >> 6;
  const float* tr = tb + n*CO_*LH_;
  if (l < LH_){
    int k0 = grp * 532;
    int k1 = k0 + 532; if (k1 > CO_*LH_) k1 = CO_*LH_;
    float acc = 0.f;
    for (int k = k0; k < k1; k++) acc += tr[k] * Wc1[k*LH_ + l];
    part[grp][l] = acc;
  }
  __syncthreads();
  if (tid < LH_){
    float a = bc1[tid];
    #pragma unroll
    for (int gg = 0; gg < 8; gg++) a += part[gg][tid];
    h1[tid] = fmaxf(a, 0.f);
  }
  __syncthreads();
  if (tid < NC_){
    float a = bc2[tid];
    #pragma unroll 10
    for (int k = 0; k < LH_; k++) a += h1[k] * Wc2[k*NC_ + tid];
    lgs[tid] = a;
  }
  __syncthreads();
  if (tid == 0){
    float m = -1e31f;
    for (int c2 = 0; c2 < NC_; c2++) m = fmaxf(m, lgs[c2]);
    float sum = 0.f;
    for (int c2 = 0; c2 < NC_; c2++) sum += __expf(lgs[c2] - m);
    float lse = m + logf(fmaxf(sum, 1e-30f));
    for (int c2 = 0; c2 < NC_; c2++)
      out[n*NC_ + c2] = __expf(lgs[c2] - lse);
    int yy = y[n];
    if ((unsigned)yy >= NC_) yy = 0;
    atomicAdd(&accs[1], -(lgs[yy] - lse));
  }
}

// ---------------- finalize losses
__global__ void k_fin(const float* __restrict__ accs, float* __restrict__ out){
  if (threadIdx.x == 0 && blockIdx.x == 0){
    out[N_*NC_]     = sane(accs[0] / (float)(N_*SZ_*LH_));
    out[N_*NC_ + 1] = sane(accs[1] / (float)N_);
  }
}

extern "C" void kernel_launch(void* const* d_in, const int* in_sizes, int n_in,
                              void* d_out, int out_size, void* d_ws, size_t ws_size,
                              hipStream_t stream){
  // ---- interface validation beacon: on ANY mismatch, launch nothing
  static const int expect[36] = {
    667200, 32, 160000, 2656, 3200, 3200,
    20000, 20000, 400, 400,
    80, 40, 40, 40, 80, 4,
    2500, 50, 35445, 85,
    22500, 450, 7500, 150,
    307200, 6144, 307200, 150,
    150, 150, 150, 150,
    212500, 50, 300, 6
  };
  if (n_in != 36 || out_size != 194 || ws_size < 14300000) return;
  for (int i = 0; i < 36; i++) if (in_sizes[i] != expect[i]) return;

  const float* x        = (const float*)d_in[0];
  const int*   y        = (const int*)d_in[1];
  const int*   ei       = (const int*)d_in[2];
  const int*   idx2     = (const int*)d_in[3];
  const float* h0s      = (const float*)d_in[4];
  const float* c0s      = (const float*)d_in[5];
  const float* lstm_Wih = (const float*)d_in[6];
  const float* lstm_Whh = (const float*)d_in[7];
  const float* lstm_bih = (const float*)d_in[8];
  const float* lstm_bhh = (const float*)d_in[9];
  const float* gcn1_W   = (const float*)d_in[10];
  const float* gcn1_b   = (const float*)d_in[11];
  const float* bn_g     = (const float*)d_in[12];
  const float* bn_b     = (const float*)d_in[13];
  const float* gcn2_W   = (const float*)d_in[14];
  const float* gcn2_b   = (const float*)d_in[15];
  const float* fc_W     = (const float*)d_in[16];
  const float* fc_b     = (const float*)d_in[17];
  const float* conv_W   = (const float*)d_in[18];
  const float* conv_b   = (const float*)d_in[19];
  const float* attn_inW = (const float*)d_in[20];
  const float* attn_inb = (const float*)d_in[21];
  const float* attn_outW= (const float*)d_in[22];
  const float* attn_outb= (const float*)d_in[23];
  const float* ff1W     = (const float*)d_in[24];
  const float* ff1b     = (const float*)d_in[25];
  const float* ff2W     = (const float*)d_in[26];
  const float* ff2b     = (const float*)d_in[27];
  const float* ln1g     = (const float*)d_in[28];
  const float* ln1b     = (const float*)d_in[29];
  const float* ln2g     = (const float*)d_in[30];
  const float* ln2b     = (const float*)d_in[31];
  const float* Wc1      = (const float*)d_in[32];
  const float* bc1      = (const float*)d_in[33];
  const float* Wc2      = (const float*)d_in[34];
  const float* bc2      = (const float*)d_in[35];
  float* out = (float*)d_out;

  // ---- workspace layout (~14.24 MB; big region X is reused across phases)
  char* wsp = (char*)d_ws;
  size_t off = 0;
  auto alloc = [&](size_t bytes)->void*{
    void* p = wsp + off;
    off = (off + bytes + 255) & ~(size_t)255;
    return p;
  };
  float* x1   = (float*)alloc((size_t)N_*T_*LH_*4);       // 2.67 MB, persistent
  float* X    = (float*)alloc((size_t)N_*T_*200*4);       // 10.7 MB region, multi-use
  float* val  = (float*)alloc((size_t)EN_*4);
  float* dinv = (float*)alloc((size_t)NODES_*4);
  float* bnsc = (float*)alloc(64*4);
  float* accs = (float*)alloc(8*4);
  int*   deg  = (int*)alloc((size_t)NODES_*4);
  int*   rowoff = (int*)alloc((size_t)(NODES_+1)*4);
  int*   wp   = (int*)alloc((size_t)NODES_*4);
  int*   col  = (int*)alloc((size_t)EN_*4);
  int*   csum = (int*)alloc(16*4);
  float* xW     = X;
  float* P0     = X;
  float* P1     = X + (size_t)NODES_*64;
  float* bnpart = X + (size_t)2*NODES_*64;
  float* Rb     = P0;
  float* tb     = X;                                  // 136000 f
  float* qkvb   = X + 136064;                         // 408000 f
  float* abuf   = X + 544128;                         // 136000 f

  k_init<<<dim3((N_*T_*LH_ + 255)/256), dim3(256), 0, stream>>>(x, x1, deg, accs);
  k_deg<<<dim3((EN_ + 255)/256), dim3(256), 0, stream>>>(ei, deg);
  k_chunksum<<<dim3(NCH_), dim3(256), 0, stream>>>(deg, csum);
  k_chunkscan<<<dim3(1), dim3(64), 0, stream>>>(csum);
  k_scan2<<<dim3(NCH_), dim3(1024), 0, stream>>>(deg, csum, rowoff, wp, dinv);
  k_scatter<<<dim3((EN_ + 255)/256), dim3(256), 0, stream>>>(ei, dinv, wp, col, val);

  for (int s = 0; s < NS_; s++){
    k_xw<<<dim3((N_*T_*200 + 255)/256), dim3(256), 0, stream>>>(x1, lstm_Wih, lstm_bih, lstm_bhh, xW, s);
    k_lstm<<<dim3(N_), dim3(256), 0, stream>>>(xW, x1, lstm_Whh, h0s, c0s, s);
    k_tonode<<<dim3((NODES_*64 + 255)/256), dim3(256), 0, stream>>>(x1, P0);
    k_gather<<<dim3(NODES_), dim3(64), 0, stream>>>(rowoff, deg, col, val, P0, P1);
    k_bnstat<<<dim3(NBNB_), dim3(256), 0, stream>>>(P1, bnpart);
    k_bnfin<<<dim3(1), dim3(256), 0, stream>>>(bnpart, gcn1_W, gcn1_b, bn_g, bn_b, bnsc, s);
    k_bnrelu_t2<<<dim3((N_*NODES_ + 255)/256), dim3(256), 0, stream>>>(P1, bnsc, gcn1_W, gcn1_b, gcn2_W, Rb, s);
    k_gcn2<<<dim3(NODES_), dim3(64), 0, stream>>>(rowoff, deg, col, val, Rb, gcn2_b, x1, s);
  }

  k_loss1<<<dim3(N_*SZ_), dim3(64), 0, stream>>>(x1, x, idx2, fc_W, fc_b, accs);
  k_conv<<<dim3(N_*CO_), dim3(64), 0, stream>>>(x1, conv_W, conv_b, tb);

  for (int l3 = 0; l3 < NL_; l3++){
    k_qkv<<<dim3((N_*CO_*150 + 255)/256), dim3(256), 0, stream>>>(tb, attn_inW, attn_inb, qkvb, l3);
    k_attn<<<dim3(NH_*CO_), dim3(128), 0, stream>>>(qkvb, abuf);
    k_proj_ln<<<dim3(N_*CO_), dim3(64), 0, stream>>>(tb, abuf, attn_outW, attn_outb, ln1g, ln1b, l3);
    k_ff<<<dim3(N_*CO_/4), dim3(512), 0, stream>>>(tb, ff1W, ff1b, ff2W, ff2b, ln2g, ln2b, l3);
  }

  k_head<<<dim3(N_), dim3(512), 0, stream>>>(tb, y, Wc1, bc1, Wc2, bc2, out, accs);
  k_fin<<<dim3(1), dim3(64), 0, stream>>>(accs, out);
}